// Round 3
// baseline (647.603 us; speedup 1.0000x reference)
//
#include <hip/hip_runtime.h>
#include <hip/hip_bf16.h>

#define B_ 64
#define N_ 8192
#define C_ 64

using short8 = __attribute__((ext_vector_type(8))) short;  // 8 bf16 (4 VGPRs)
using f32x4  = __attribute__((ext_vector_type(4))) float;

#define MFMA16(a, b, c) __builtin_amdgcn_mfma_f32_16x16x32_bf16((a), (b), (c), 0, 0, 0)

__device__ inline unsigned short f2bf(float f) {
  union { float f; unsigned int u; } v; v.f = f;
  unsigned int r = v.u + 0x7FFFu + ((v.u >> 16) & 1u);   // RNE
  return (unsigned short)(r >> 16);
}

// ws layout (f32 indices unless noted):
//   stats   [0,1024)          8 copies x 128
//   meanr   [1024,1152)
//   pmax    [1152,33920)      512*64
//   W_lq    [33920,34080)     [10][16]   composite x->xq
//   b_lq    [34080,34096)
//   W_rk    [34096,34304)     [13][16]   composite y->yk
//   b_rk    [34304,34320)
//   W_rv    [34320,35152)     [13][64]   composite y->yv
//   b_rv    [35152,35216)
//   then bf16 (ushort):
//   W_lTg   [64][40]  (2560)  B-operand for X = x@W_l (k 10..39 zero)
//   WtBg    [64][64]  (4096)  B-operand for t = Z@W_t^T
//   ykg     [N][64][16]       (8.4M shorts)
//   yvtg    [N][64][64]       (33.5M shorts)  — OVERLAID by tg in k1
// total ~84 MB

// ---- k0: composites + bf16 weight layouts + zero stats -------------------
__global__ void k0_prep(const float* __restrict__ W_l, const float* __restrict__ b_l,
                        const float* __restrict__ W_r, const float* __restrict__ b_r,
                        const float* __restrict__ W_qk, const float* __restrict__ W_v,
                        const float* __restrict__ b_v, const float* __restrict__ W_t,
                        float* __restrict__ wsf) {
  const int tid = threadIdx.x;
  float* W_lq_ = wsf + 33920;
  float* b_lq_ = wsf + 34080;
  float* W_rk_ = wsf + 34096;
  float* b_rk_ = wsf + 34304;
  float* W_rv_ = wsf + 34320;
  float* b_rv_ = wsf + 35152;
  unsigned short* W_lTg = (unsigned short*)(wsf + 35216);
  unsigned short* WtBg  = W_lTg + 2560;
  if (blockIdx.x == 0) {
    for (int i = tid; i < 400; i += 256) {
      if (i < 160) {
        int k = i >> 4, d = i & 15;
        float s = 0.f;
        for (int c = 0; c < 64; ++c) s = fmaf(W_l[k * 64 + c], W_qk[d * 64 + c], s);
        W_lq_[k * 16 + d] = s;
      } else if (i < 176) {
        int d = i - 160;
        float s = 0.f;
        for (int c = 0; c < 64; ++c) s = fmaf(b_l[c], W_qk[d * 64 + c], s);
        b_lq_[d] = s;
      } else if (i < 384) {
        int j = i - 176, k = j >> 4, d = j & 15;
        float s = 0.f;
        for (int c = 0; c < 64; ++c) s = fmaf(W_r[k * 64 + c], W_qk[d * 64 + c], s);
        W_rk_[k * 16 + d] = s;
      } else {
        int d = i - 384;
        float s = 0.f;
        for (int c = 0; c < 64; ++c) s = fmaf(b_r[c], W_qk[d * 64 + c], s);
        b_rk_[d] = s;
      }
    }
  } else if (blockIdx.x == 1) {
    for (int i = tid; i < 896; i += 256) {
      if (i < 832) {
        int k = i >> 6, c = i & 63;
        float s = 0.f;
        for (int j = 0; j < 64; ++j) s = fmaf(W_r[k * 64 + j], W_v[c * 64 + j], s);
        W_rv_[k * 64 + c] = s;
      } else {
        int c = i - 832;
        float s = b_v[c];
        for (int j = 0; j < 64; ++j) s = fmaf(b_r[j], W_v[c * 64 + j], s);
        b_rv_[c] = s;
      }
    }
  } else if (blockIdx.x == 2) {
    for (int i = tid; i < 2560; i += 256) {
      int c = i / 40, k = i - c * 40;
      W_lTg[i] = (k < 10) ? f2bf(W_l[k * 64 + c]) : (unsigned short)0;
    }
  } else if (blockIdx.x == 3) {
    for (int i = tid; i < 4096; i += 256) WtBg[i] = f2bf(W_t[i]);
  } else {
    for (int i = tid; i < 1024; i += 256) wsf[i] = 0.f;
  }
}

// ---- kA: y -> yk[n][e][16], yv_t[n][c][e] (composite weights) ------------
__global__ __launch_bounds__(256)
void kA_yprep(const float* __restrict__ y, const float* __restrict__ wsf,
              unsigned short* __restrict__ ykg, unsigned short* __restrict__ yvtg) {
  const int tid  = threadIdx.x;
  const int lane = tid & 63;       // e
  const int w    = tid >> 6;       // wave: c-range w*16.., d-range w*4..
  const float* W_rk_ = wsf + 34096;
  const float* b_rk_ = wsf + 34304;
  const float* W_rv_ = wsf + 34320;
  const float* b_rv_ = wsf + 35152;
  const int n0 = blockIdx.x * 4;
  for (int dn = 0; dn < 4; ++dn) {
    const int n = n0 + dn;
    const float* yp = y + ((size_t)lane * N_ + n) * 13;
    float yv[13];
#pragma unroll
    for (int k = 0; k < 13; ++k) yv[k] = yp[k];
    // yk: 4 d's, packed
    unsigned int pk[2];
#pragma unroll
    for (int dd = 0; dd < 2; ++dd) {
      const int d0 = w * 4 + dd * 2;
      float a0 = b_rk_[d0], a1 = b_rk_[d0 + 1];
#pragma unroll
      for (int k = 0; k < 13; ++k) {
        a0 = fmaf(yv[k], W_rk_[k * 16 + d0], a0);
        a1 = fmaf(yv[k], W_rk_[k * 16 + d0 + 1], a1);
      }
      pk[dd] = (unsigned int)f2bf(a0) | ((unsigned int)f2bf(a1) << 16);
    }
    *(uint2*)&ykg[(size_t)n * 1024 + lane * 16 + w * 4] = make_uint2(pk[0], pk[1]);
    // yv_t: 16 c's, stored transposed [c][e]
    unsigned short* op = yvtg + (size_t)n * 4096 + lane;
#pragma unroll
    for (int i = 0; i < 16; ++i) {
      const int c = w * 16 + i;
      float s = b_rv_[c];
#pragma unroll
      for (int k = 0; k < 13; ++k) s = fmaf(yv[k], W_rv_[k * 64 + c], s);
      op[c * 64] = f2bf(s);
    }
  }
}

// ---- k1: per-point attention chain, one block per n ----------------------
__global__ __launch_bounds__(256)
void k1_attn(const float* __restrict__ x, const float* __restrict__ wsf,
             const unsigned short* __restrict__ ykg,
             unsigned short* yvtg,                 // read yv, then OVERLAY-write t
             const float* __restrict__ b_l, const float* __restrict__ b_t,
             float* __restrict__ stats) {
  __shared__ short attnZ[9216];   // [wave][attn 16x72 | Z 16x72]
  __shared__ float scr[512];
  const float* W_lq_ = wsf + 33920;
  const float* b_lq_ = wsf + 34080;
  const unsigned short* W_lTg = (const unsigned short*)(wsf + 35216);
  const unsigned short* WtBg  = W_lTg + 2560;

  const int n    = blockIdx.x;
  const int tid  = threadIdx.x;
  const int w    = tid >> 6;
  const int lane = tid & 63;
  const int l15  = lane & 15;
  const int q    = lane >> 4;
  const int r0   = w * 16;
  short* const aw = attnZ + w * 2304;        // attn [16][72]
  short* const Zw = aw + 1152;               // Z    [16][72]

  // ---- x row (r0+l15), xq values d = q*4..q*4+3 ----
  float xv[10];
  const float* xp = x + ((size_t)(r0 + l15) * N_ + n) * 10;
#pragma unroll
  for (int k = 0; k < 10; ++k) xv[k] = xp[k];
  float xqv[4];
  {
    const float4 bq = *(const float4*)&b_lq_[q * 4];
    float4 acc = bq;
#pragma unroll
    for (int k = 0; k < 10; ++k) {
      const float4 wq = *(const float4*)&W_lq_[k * 16 + q * 4];
      acc.x = fmaf(xv[k], wq.x, acc.x);
      acc.y = fmaf(xv[k], wq.y, acc.y);
      acc.z = fmaf(xv[k], wq.z, acc.z);
      acc.w = fmaf(xv[k], wq.w, acc.w);
    }
    xqv[0] = acc.x; xqv[1] = acc.y; xqv[2] = acc.z; xqv[3] = acc.w;
  }
  // gather xq A-frag: lane (l15,q) wants d = q*8+j (valid q<2)
  short8 aq;
  const int sbase = ((lane >> 4) << 5) + l15;   // (q*2)*16 + l15
#pragma unroll
  for (int j = 0; j < 8; ++j) {
    const float g = __shfl(xqv[j & 3], sbase + ((j >> 2) << 4));
    aq[j] = (q < 2) ? (short)f2bf(g) : (short)0;
  }

  // ---- E = xq yk^T ----
  const unsigned short* ykp = ykg + (size_t)n * 1024;
  f32x4 E[4];
#pragma unroll
  for (int f = 0; f < 4; ++f) {
    short8 bk = (short8)(short)0;
    if (q < 2) bk = *(const short8*)&ykp[(f * 16 + l15) * 16 + q * 8];
    E[f] = MFMA16(aq, bk, ((f32x4){0.f, 0.f, 0.f, 0.f}));
  }

  // ---- softmax over e (no max-subtract: |E| << 1) ----
  float inv_r[4];
#pragma unroll
  for (int j = 0; j < 4; ++j) {
    float s = 0.f;
#pragma unroll
    for (int f = 0; f < 4; ++f) { E[f][j] = __expf(E[f][j]); s += E[f][j]; }
    s += __shfl_xor(s, 1);
    s += __shfl_xor(s, 2);
    s += __shfl_xor(s, 4);
    s += __shfl_xor(s, 8);
    inv_r[j] = 1.0f / s;
  }
  // ---- column sums (L1 renorm) ----
#pragma unroll
  for (int f = 0; f < 4; ++f) {
    float cs = E[f][0] * inv_r[0] + E[f][1] * inv_r[1] + E[f][2] * inv_r[2] + E[f][3] * inv_r[3];
    cs += __shfl_xor(cs, 16);
    cs += __shfl_xor(cs, 32);
    if (lane < 16) scr[w * 64 + f * 16 + l15] = cs;
  }
  __syncthreads();  // S3
  float csvv[4];
#pragma unroll
  for (int f = 0; f < 4; ++f) {
    const int col = f * 16 + l15;
    csvv[f] = 1.0f / (1e-9f + scr[col] + scr[64 + col] + scr[128 + col] + scr[192 + col]);
  }
  // ---- attn -> per-wave LDS (A-layout source) ----
#pragma unroll
  for (int f = 0; f < 4; ++f)
#pragma unroll
    for (int j = 0; j < 4; ++j)
      aw[(q * 4 + j) * 72 + f * 16 + l15] = (short)f2bf(E[f][j] * inv_r[j] * csvv[f]);

  // ---- yr = attn @ yv (yv B-frags direct from global) ----
  const short8 aA0 = *(const short8*)&aw[l15 * 72 + q * 8];
  const short8 aA1 = *(const short8*)&aw[l15 * 72 + 32 + q * 8];
  const unsigned short* yvp = yvtg + (size_t)n * 4096;
  f32x4 yr[4];
#pragma unroll
  for (int f = 0; f < 4; ++f) {
    const short8 b0 = *(const short8*)&yvp[(f * 16 + l15) * 64 + q * 8];
    const short8 b1 = *(const short8*)&yvp[(f * 16 + l15) * 64 + 32 + q * 8];
    yr[f] = MFMA16(aA0, b0, ((f32x4){0.f, 0.f, 0.f, 0.f}));
    yr[f] = MFMA16(aA1, b1, yr[f]);
  }

  // ---- X via MFMA (zero-padded K), Z = X + b_l - yr -> per-wave LDS ----
  short8 ax = (short8)(short)0;
  if (q == 0) {
#pragma unroll
    for (int j = 0; j < 8; ++j) ax[j] = (short)f2bf(xv[j]);
  } else if (q == 1) {
    ax[0] = (short)f2bf(xv[8]);
    ax[1] = (short)f2bf(xv[9]);
  }
#pragma unroll
  for (int f = 0; f < 4; ++f) {
    const short8 bL = *(const short8*)&W_lTg[(f * 16 + l15) * 40 + q * 8];
    f32x4 Xf = MFMA16(ax, bL, ((f32x4){0.f, 0.f, 0.f, 0.f}));
    const float blv = b_l[f * 16 + l15];
#pragma unroll
    for (int j = 0; j < 4; ++j)
      Zw[(q * 4 + j) * 72 + f * 16 + l15] = (short)f2bf(Xf[j] + blv - yr[f][j]);
  }
  __syncthreads();  // overlay fence: all yvtg reads done before t stores; scr reuse fence

  // ---- t = Z @ W_t^T + b_t ----
  const short8 aZ0 = *(const short8*)&Zw[l15 * 72 + q * 8];
  const short8 aZ1 = *(const short8*)&Zw[l15 * 72 + 32 + q * 8];
  unsigned short* tp = yvtg + (size_t)n * 4096;   // OVERLAY: tg[n][b][c]
#pragma unroll
  for (int f = 0; f < 4; ++f) {
    const short8 bt0 = *(const short8*)&WtBg[(f * 16 + l15) * 64 + q * 8];
    const short8 bt1 = *(const short8*)&WtBg[(f * 16 + l15) * 64 + 32 + q * 8];
    const float btv = b_t[f * 16 + l15];
    f32x4 t = {btv, btv, btv, btv};
    t = MFMA16(aZ0, bt0, t);
    t = MFMA16(aZ1, bt1, t);
    float s = 0.f, ss = 0.f;
#pragma unroll
    for (int j = 0; j < 4; ++j) {
      const float v = t[j];
      s += v; ss = fmaf(v, v, ss);
      tp[(r0 + q * 4 + j) * 64 + f * 16 + l15] = f2bf(v);
    }
    s  += __shfl_xor(s, 16);  s  += __shfl_xor(s, 32);
    ss += __shfl_xor(ss, 16); ss += __shfl_xor(ss, 32);
    if (lane < 16) {
      scr[w * 64 + f * 16 + l15]       = s;
      scr[256 + w * 64 + f * 16 + l15] = ss;
    }
  }
  __syncthreads();
  if (tid < 64) {
    const float s  = scr[tid] + scr[64 + tid] + scr[128 + tid] + scr[192 + tid];
    const float ss = scr[256 + tid] + scr[320 + tid] + scr[384 + tid] + scr[448 + tid];
    float* st = stats + (n & 7) * 128;
    atomicAdd(&st[tid], s);
    atomicAdd(&st[64 + tid], ss);
  }
}

// ---- k2: finalize BN stats ----------------------------------------------
__global__ void k2_stats(const float* __restrict__ stats, float* __restrict__ meanr) {
  const int c = threadIdx.x;
  if (c < 64) {
    float s = 0.f, ss = 0.f;
    for (int r = 0; r < 8; ++r) { s += stats[r * 128 + c]; ss += stats[r * 128 + 64 + c]; }
    const float inv = 1.0f / (float)(B_ * N_);
    const float mu = s * inv;
    const float var = fmaf(ss, inv, -mu * mu);
    meanr[c] = mu;
    meanr[64 + c] = rsqrtf(var + 1e-5f);
  }
}

// ---- k3: recompute X, BN+ReLU+residual, partial max over n ---------------
__global__ __launch_bounds__(256)
void k3_max(const float* __restrict__ x, const float* __restrict__ W_l,
            const float* __restrict__ b_l, const float* __restrict__ gamma,
            const float* __restrict__ beta, const unsigned short* __restrict__ tg,
            const float* __restrict__ meanr, float* __restrict__ pmax)
{
  const int b = blockIdx.x >> 3;
  const int chunk = blockIdx.x & 7;
  const int c = threadIdx.x & 63;
  const int sub = threadIdx.x >> 6;
  float wl[10];
#pragma unroll
  for (int k = 0; k < 10; ++k) wl[k] = W_l[k * 64 + c];
  const float bl = b_l[c];
  const float g = gamma[c], be = beta[c];
  const float mu = meanr[c], rs = meanr[64 + c];
  float m = -1e30f;
  const int nbase = chunk * 1024 + sub;
  for (int j = 0; j < 256; ++j) {
    const int n = nbase + j * 4;
    const float* xp = x + ((size_t)b * N_ + n) * 10;
    float X = bl;
#pragma unroll
    for (int k = 0; k < 10; ++k) X = fmaf(xp[k], wl[k], X);
    union { unsigned int u; float f; } tv;
    tv.u = ((unsigned int)tg[(size_t)n * 4096 + b * 64 + c]) << 16;
    const float tn = fmaf(g * (tv.f - mu), rs, be);
    m = fmaxf(m, X + fmaxf(tn, 0.f));
  }
  __shared__ float sm[4][64];
  sm[sub][c] = m;
  __syncthreads();
  if (threadIdx.x < 64) {
    const float r = fmaxf(fmaxf(sm[0][c], sm[1][c]), fmaxf(sm[2][c], sm[3][c]));
    pmax[(size_t)blockIdx.x * 64 + c] = r;
  }
}

// ---- k4: final max over chunks -------------------------------------------
__global__ void k4_final(const float* __restrict__ pmax, float* __restrict__ out) {
  const int b = blockIdx.x, c = threadIdx.x;
  float m = -1e30f;
  for (int ch = 0; ch < 8; ++ch) m = fmaxf(m, pmax[((size_t)b * 8 + ch) * 64 + c]);
  out[b * 64 + c] = m;
}

// ---- launcher -------------------------------------------------------------
extern "C" void kernel_launch(void* const* d_in, const int* in_sizes, int n_in,
                              void* d_out, int out_size, void* d_ws, size_t ws_size,
                              hipStream_t stream) {
  const float* x     = (const float*)d_in[0];
  const float* y     = (const float*)d_in[1];
  const float* W_l   = (const float*)d_in[2];
  const float* b_l   = (const float*)d_in[3];
  const float* W_r   = (const float*)d_in[4];
  const float* b_r   = (const float*)d_in[5];
  const float* W_qk  = (const float*)d_in[6];
  const float* W_v   = (const float*)d_in[7];
  const float* b_v   = (const float*)d_in[8];
  const float* W_t   = (const float*)d_in[9];
  const float* b_t   = (const float*)d_in[10];
  const float* gamma = (const float*)d_in[11];
  const float* beta  = (const float*)d_in[12];
  float* out = (float*)d_out;

  float* wsf = (float*)d_ws;
  float* stats = wsf;
  float* meanr = wsf + 1024;
  float* pmax  = wsf + 1152;
  unsigned short* W_lTg = (unsigned short*)(wsf + 35216);
  unsigned short* ykg   = W_lTg + 2560 + 4096;
  unsigned short* yvtg  = ykg + (size_t)N_ * 1024;   // also tg (overlay)

  hipLaunchKernelGGL(k0_prep, dim3(5), dim3(256), 0, stream,
                     W_l, b_l, W_r, b_r, W_qk, W_v, b_v, W_t, wsf);
  hipLaunchKernelGGL(kA_yprep, dim3(N_ / 4), dim3(256), 0, stream, y, wsf, ykg, yvtg);
  hipLaunchKernelGGL(k1_attn, dim3(N_), dim3(256), 0, stream,
                     x, wsf, ykg, yvtg, b_l, b_t, stats);
  hipLaunchKernelGGL(k2_stats, dim3(1), dim3(64), 0, stream, stats, meanr);
  hipLaunchKernelGGL(k3_max, dim3(512), dim3(256), 0, stream,
                     x, W_l, b_l, gamma, beta, yvtg, meanr, pmax);
  hipLaunchKernelGGL(k4_final, dim3(64), dim3(64), 0, stream, pmax, out);
}

// Round 4
// 248.866 us; speedup vs baseline: 2.6022x; 2.6022x over previous
//
#include <hip/hip_runtime.h>
#include <hip/hip_bf16.h>

#define B_ 64
#define N_ 8192
#define C_ 64

using short8 = __attribute__((ext_vector_type(8))) short;  // 8 bf16 (4 VGPRs)
using f32x4  = __attribute__((ext_vector_type(4))) float;

#define MFMA16(a, b, c) __builtin_amdgcn_mfma_f32_16x16x32_bf16((a), (b), (c), 0, 0, 0)

__device__ inline unsigned short f2bf(float f) {
  union { float f; unsigned int u; } v; v.f = f;
  unsigned int r = v.u + 0x7FFFu + ((v.u >> 16) & 1u);   // RNE
  return (unsigned short)(r >> 16);
}

// ws layout:
//  f32: stats[0,1024) | meanr[1024,1152) | pmax[1152,33920)
//       b_lq[33920,33936) | b_rk[33936,33952) | b_rv[33952,34016)
//  ushort (wb = wsf+34016):
//       BLQ[16][32] @0 | BRK[16][32] @512 | BL[64][32] @1024
//       BRV[64][32] @3072 | BT[64][64] @5120 | tg[N][64][64] @9216
// A-tile k-slot convention: k 0..9 = x, 10..15 = 0, 16..28 = y, 29..31 = 0.

// ---- k0: weight prep (4 blocks) ------------------------------------------
__global__ void k0_prep(const float* __restrict__ W_l, const float* __restrict__ b_l,
                        const float* __restrict__ W_r, const float* __restrict__ b_r,
                        const float* __restrict__ W_qk, const float* __restrict__ W_v,
                        const float* __restrict__ b_v, const float* __restrict__ W_t,
                        float* __restrict__ wsf) {
  const int tid = threadIdx.x;
  float* b_lq_ = wsf + 33920;
  float* b_rk_ = wsf + 33936;
  float* b_rv_ = wsf + 33952;
  unsigned short* wb = (unsigned short*)(wsf + 34016);
  unsigned short* BLQ = wb;
  unsigned short* BRK = wb + 512;
  unsigned short* BL  = wb + 1024;
  unsigned short* BRV = wb + 3072;
  unsigned short* BT  = wb + 5120;
  if (blockIdx.x == 0) {
    for (int i = tid; i < 512; i += 256) {       // BLQ[d][kk]: W_lq = W_l . W_qk^T
      int d = i >> 5, kk = i & 31;
      unsigned short o = 0;
      if (kk < 10) {
        float s = 0.f;
        for (int c = 0; c < 64; ++c) s = fmaf(W_l[kk * 64 + c], W_qk[d * 64 + c], s);
        o = f2bf(s);
      }
      BLQ[i] = o;
    }
    for (int i = tid; i < 512; i += 256) {       // BRK[d][kk]: W_rk = W_r . W_qk^T
      int d = i >> 5, kk = i & 31, k = kk - 16;
      unsigned short o = 0;
      if (k >= 0 && k < 13) {
        float s = 0.f;
        for (int c = 0; c < 64; ++c) s = fmaf(W_r[k * 64 + c], W_qk[d * 64 + c], s);
        o = f2bf(s);
      }
      BRK[i] = o;
    }
    if (tid < 32) {
      int d = tid & 15;
      const float* bb = (tid < 16) ? b_l : b_r;
      float s = 0.f;
      for (int c = 0; c < 64; ++c) s = fmaf(bb[c], W_qk[d * 64 + c], s);
      ((tid < 16) ? b_lq_ : b_rk_)[d] = s;
    }
  } else if (blockIdx.x == 1) {
    for (int i = tid; i < 2048; i += 256) {      // BRV[c][kk]: W_rv = W_r . W_v^T
      int c = i >> 5, kk = i & 31, k = kk - 16;
      unsigned short o = 0;
      if (k >= 0 && k < 13) {
        float s = 0.f;
        for (int j = 0; j < 64; ++j) s = fmaf(W_r[k * 64 + j], W_v[c * 64 + j], s);
        o = f2bf(s);
      }
      BRV[i] = o;
    }
    if (tid < 64) {
      float s = b_v[tid];
      for (int j = 0; j < 64; ++j) s = fmaf(b_r[j], W_v[tid * 64 + j], s);
      b_rv_[tid] = s;
    }
  } else if (blockIdx.x == 2) {
    for (int i = tid; i < 2048; i += 256) {      // BL[c][kk] = W_l[kk][c]
      int c = i >> 5, kk = i & 31;
      BL[i] = (kk < 10) ? f2bf(W_l[kk * 64 + c]) : (unsigned short)0;
    }
    for (int i = tid; i < 1024; i += 256) wsf[i] = 0.f;   // stats
  } else {
    for (int i = tid; i < 4096; i += 256) BT[i] = f2bf(W_t[i]);   // BT[d][k] = W_t[d][k]
  }
}

// ---- k1: fused per-point chain, one block per n --------------------------
__global__ __launch_bounds__(256, 4)
void k1_attn(const float* __restrict__ x, const float* __restrict__ y,
             const float* __restrict__ wsf,
             const float* __restrict__ b_l, const float* __restrict__ b_t,
             float* __restrict__ stats) {
  // LDS = (2560 + 1536 + 1536 + 4608 + 9216)*2 + 2048 = 40960 B -> 4 blocks/CU
  __shared__ __align__(16) short Axy[64 * 40];   // [b][k-slots 0..39]
  __shared__ __align__(16) short xkA[64 * 24];   // xq A-tile [b][d 0..15]
  __shared__ __align__(16) short ykB[64 * 24];   // yk B-tile [e][d 0..15]
  __shared__ __align__(16) short yvT[64 * 72];   // [c][e]
  __shared__ __align__(16) short aZ[4 * 2304];   // per-wave: attn[16][72] | Z[16][72]
  __shared__ float scr[512];

  const float* b_lq_ = wsf + 33920;
  const float* b_rk_ = wsf + 33936;
  const float* b_rv_ = wsf + 33952;
  const unsigned short* wbase = (const unsigned short*)(wsf + 34016);
  const unsigned short* BLQ = wbase;
  const unsigned short* BRK = wbase + 512;
  const unsigned short* BL  = wbase + 1024;
  const unsigned short* BRV = wbase + 3072;
  const unsigned short* BT  = wbase + 5120;
  unsigned short* tg = (unsigned short*)(wsf + 34016) + 9216;

  const int n    = blockIdx.x;
  const int tid  = threadIdx.x;
  const int w    = tid >> 6;
  const int lane = tid & 63;
  const int l15  = lane & 15;
  const int q    = lane >> 4;
  const int r0   = w * 16;
  short* const aw = aZ + w * 2304;       // attn [16][72]
  short* const Zw = aw + 1152;           // Z    [16][72]

  // ---- stage x,y rows into unified A tile ----
  {
    const int b = tid >> 2, i = tid & 3;
    const float* xp = x + ((size_t)b * N_ + n) * 10;
    const float* yp = y + ((size_t)b * N_ + n) * 13;
    short* Ar = Axy + b * 40;
    Ar[i]      = (short)f2bf(xp[i]);
    Ar[i + 4]  = (short)f2bf(xp[i + 4]);
    Ar[i + 8]  = (i + 8 < 10) ? (short)f2bf(xp[i + 8]) : (short)0;
    Ar[12 + i] = 0;
    Ar[16 + i]      = (short)f2bf(yp[i]);
    Ar[20 + i]      = (short)f2bf(yp[i + 4]);
    Ar[24 + i]      = (short)f2bf(yp[i + 8]);
    Ar[28 + i]      = (i + 12 < 13) ? (short)f2bf(yp[i + 12]) : (short)0;
  }
  __syncthreads();  // S1

  // ---- unified A-frag (K=32 in one b128) ----
  const short8 aA = *(const short8*)&Axy[(r0 + l15) * 40 + q * 8];

  // ---- xq, yk (1 MFMA each), X, yv (4 each) ----
  f32x4 xq, yk, X[4], yv[4];
  {
    const short8 bq = *(const short8*)&BLQ[l15 * 32 + q * 8];
    const float bl1 = b_lq_[l15];
    xq = MFMA16(aA, bq, ((f32x4){bl1, bl1, bl1, bl1}));
    const short8 bk = *(const short8*)&BRK[l15 * 32 + q * 8];
    const float bk1 = b_rk_[l15];
    yk = MFMA16(aA, bk, ((f32x4){bk1, bk1, bk1, bk1}));
  }
#pragma unroll
  for (int f = 0; f < 4; ++f) {
    const int c = f * 16 + l15;
    const short8 bl = *(const short8*)&BL[c * 32 + q * 8];
    const float bX = b_l[c];
    X[f] = MFMA16(aA, bl, ((f32x4){bX, bX, bX, bX}));
    const short8 bv = *(const short8*)&BRV[c * 32 + q * 8];
    const float bV = b_rv_[c];
    yv[f] = MFMA16(aA, bv, ((f32x4){bV, bV, bV, bV}));
  }
  // C-layout scatters
#pragma unroll
  for (int j = 0; j < 4; ++j) {
    xkA[(r0 + q * 4 + j) * 24 + l15] = (short)f2bf(xq[j]);
    ykB[(r0 + q * 4 + j) * 24 + l15] = (short)f2bf(yk[j]);
  }
#pragma unroll
  for (int f = 0; f < 4; ++f)
#pragma unroll
    for (int j = 0; j < 4; ++j)
      yvT[(f * 16 + l15) * 72 + (r0 + q * 4 + j)] = (short)f2bf(yv[f][j]);
  __syncthreads();  // S2

  // ---- E = xq yk^T (K=16 real, upper half zero) ----
  const short8 z8 = (short8)(short)0;
  const short8 aq = (q < 2) ? *(const short8*)&xkA[(r0 + l15) * 24 + q * 8] : z8;
  f32x4 E[4];
#pragma unroll
  for (int f = 0; f < 4; ++f) {
    const short8 bk = (q < 2) ? *(const short8*)&ykB[(f * 16 + l15) * 24 + q * 8] : z8;
    E[f] = MFMA16(aq, bk, ((f32x4){0.f, 0.f, 0.f, 0.f}));
  }

  // ---- softmax over e (|E|<<1: no max-subtract) ----
  float inv_r[4];
#pragma unroll
  for (int j = 0; j < 4; ++j) {
    float s = 0.f;
#pragma unroll
    for (int f = 0; f < 4; ++f) { E[f][j] = __expf(E[f][j]); s += E[f][j]; }
    s += __shfl_xor(s, 1);
    s += __shfl_xor(s, 2);
    s += __shfl_xor(s, 4);
    s += __shfl_xor(s, 8);
    inv_r[j] = 1.0f / s;
  }
  // ---- column sums (L1 renorm) ----
#pragma unroll
  for (int f = 0; f < 4; ++f) {
    float cs = E[f][0] * inv_r[0] + E[f][1] * inv_r[1] + E[f][2] * inv_r[2] + E[f][3] * inv_r[3];
    cs += __shfl_xor(cs, 16);
    cs += __shfl_xor(cs, 32);
    if (lane < 16) scr[w * 64 + f * 16 + l15] = cs;
  }
  __syncthreads();  // S3
  float csvv[4];
#pragma unroll
  for (int f = 0; f < 4; ++f) {
    const int col = f * 16 + l15;
    csvv[f] = 1.0f / (1e-9f + scr[col] + scr[64 + col] + scr[128 + col] + scr[192 + col]);
  }
  // ---- attn -> per-wave LDS tile (wave-local; DS ops in-order, no barrier) ----
#pragma unroll
  for (int f = 0; f < 4; ++f)
#pragma unroll
    for (int j = 0; j < 4; ++j)
      aw[(q * 4 + j) * 72 + f * 16 + l15] = (short)f2bf(E[f][j] * inv_r[j] * csvv[f]);

  // ---- yr = attn @ yv ; Z = X - yr -> per-wave LDS ----
  const short8 aA0 = *(const short8*)&aw[l15 * 72 + q * 8];
  const short8 aA1 = *(const short8*)&aw[l15 * 72 + 32 + q * 8];
#pragma unroll
  for (int f = 0; f < 4; ++f) {
    const short8 b0 = *(const short8*)&yvT[(f * 16 + l15) * 72 + q * 8];
    const short8 b1 = *(const short8*)&yvT[(f * 16 + l15) * 72 + 32 + q * 8];
    f32x4 yr = MFMA16(aA0, b0, ((f32x4){0.f, 0.f, 0.f, 0.f}));
    yr = MFMA16(aA1, b1, yr);
#pragma unroll
    for (int j = 0; j < 4; ++j)
      Zw[(q * 4 + j) * 72 + f * 16 + l15] = (short)f2bf(X[f][j] - yr[j]);
  }

  // ---- t = Z @ W_t^T + b_t ; store + stats ----
  const short8 aZ0 = *(const short8*)&Zw[l15 * 72 + q * 8];
  const short8 aZ1 = *(const short8*)&Zw[l15 * 72 + 32 + q * 8];
  unsigned short* tp = tg + (size_t)n * 4096;
  f32x4 t[4];
#pragma unroll
  for (int f = 0; f < 4; ++f) {
    const int c = f * 16 + l15;
    const short8 bt0 = *(const short8*)&BT[c * 64 + q * 8];
    const short8 bt1 = *(const short8*)&BT[c * 64 + 32 + q * 8];
    const float bT = b_t[c];
    t[f] = MFMA16(aZ0, bt0, ((f32x4){bT, bT, bT, bT}));
    t[f] = MFMA16(aZ1, bt1, t[f]);
#pragma unroll
    for (int j = 0; j < 4; ++j)
      tp[(r0 + q * 4 + j) * 64 + c] = f2bf(t[f][j]);
  }
  __syncthreads();  // S4: csv reads done before scr reuse
#pragma unroll
  for (int f = 0; f < 4; ++f) {
    float s = 0.f, ss = 0.f;
#pragma unroll
    for (int j = 0; j < 4; ++j) { s += t[f][j]; ss = fmaf(t[f][j], t[f][j], ss); }
    s  += __shfl_xor(s, 16);  s  += __shfl_xor(s, 32);
    ss += __shfl_xor(ss, 16); ss += __shfl_xor(ss, 32);
    if (lane < 16) {
      scr[w * 64 + f * 16 + l15]       = s;
      scr[256 + w * 64 + f * 16 + l15] = ss;
    }
  }
  __syncthreads();  // S5
  if (tid < 64) {
    const float s  = scr[tid] + scr[64 + tid] + scr[128 + tid] + scr[192 + tid];
    const float ss = scr[256 + tid] + scr[320 + tid] + scr[384 + tid] + scr[448 + tid];
    float* st = stats + (n & 7) * 128;
    atomicAdd(&st[tid], s);
    atomicAdd(&st[64 + tid], ss);
  }
}

// ---- k2: finalize BN stats ----------------------------------------------
__global__ void k2_stats(const float* __restrict__ stats, float* __restrict__ meanr) {
  const int c = threadIdx.x;
  if (c < 64) {
    float s = 0.f, ss = 0.f;
    for (int r = 0; r < 8; ++r) { s += stats[r * 128 + c]; ss += stats[r * 128 + 64 + c]; }
    const float inv = 1.0f / (float)(B_ * N_);
    const float mu = s * inv;
    const float var = fmaf(ss, inv, -mu * mu);
    meanr[c] = mu;
    meanr[64 + c] = rsqrtf(var + 1e-5f);
  }
}

// ---- k3: recompute X, BN+ReLU+residual, partial max over n ---------------
__global__ __launch_bounds__(256)
void k3_max(const float* __restrict__ x, const float* __restrict__ W_l,
            const float* __restrict__ b_l, const float* __restrict__ gamma,
            const float* __restrict__ beta, const unsigned short* __restrict__ tg,
            const float* __restrict__ meanr, float* __restrict__ pmax)
{
  const int b = blockIdx.x >> 3;
  const int chunk = blockIdx.x & 7;
  const int c = threadIdx.x & 63;
  const int sub = threadIdx.x >> 6;
  float wl[10];
#pragma unroll
  for (int k = 0; k < 10; ++k) wl[k] = W_l[k * 64 + c];
  const float bl = b_l[c];
  const float g = gamma[c], be = beta[c];
  const float mu = meanr[c], rs = meanr[64 + c];
  float m = -1e30f;
  const int nbase = chunk * 1024 + sub;
  for (int j = 0; j < 256; ++j) {
    const int n = nbase + j * 4;
    const float* xp = x + ((size_t)b * N_ + n) * 10;
    float X = bl;
#pragma unroll
    for (int k = 0; k < 10; ++k) X = fmaf(xp[k], wl[k], X);
    union { unsigned int u; float f; } tv;
    tv.u = ((unsigned int)tg[(size_t)n * 4096 + b * 64 + c]) << 16;
    const float tn = fmaf(g * (tv.f - mu), rs, be);
    m = fmaxf(m, X + fmaxf(tn, 0.f));
  }
  __shared__ float sm[4][64];
  sm[sub][c] = m;
  __syncthreads();
  if (threadIdx.x < 64) {
    const float r = fmaxf(fmaxf(sm[0][c], sm[1][c]), fmaxf(sm[2][c], sm[3][c]));
    pmax[(size_t)blockIdx.x * 64 + c] = r;
  }
}

// ---- k4: final max over chunks -------------------------------------------
__global__ void k4_final(const float* __restrict__ pmax, float* __restrict__ out) {
  const int b = blockIdx.x, c = threadIdx.x;
  float m = -1e30f;
  for (int ch = 0; ch < 8; ++ch) m = fmaxf(m, pmax[((size_t)b * 8 + ch) * 64 + c]);
  out[b * 64 + c] = m;
}

// ---- launcher -------------------------------------------------------------
extern "C" void kernel_launch(void* const* d_in, const int* in_sizes, int n_in,
                              void* d_out, int out_size, void* d_ws, size_t ws_size,
                              hipStream_t stream) {
  const float* x     = (const float*)d_in[0];
  const float* y     = (const float*)d_in[1];
  const float* W_l   = (const float*)d_in[2];
  const float* b_l   = (const float*)d_in[3];
  const float* W_r   = (const float*)d_in[4];
  const float* b_r   = (const float*)d_in[5];
  const float* W_qk  = (const float*)d_in[6];
  const float* W_v   = (const float*)d_in[7];
  const float* b_v   = (const float*)d_in[8];
  const float* W_t   = (const float*)d_in[9];
  const float* b_t   = (const float*)d_in[10];
  const float* gamma = (const float*)d_in[11];
  const float* beta  = (const float*)d_in[12];
  float* out = (float*)d_out;

  float* wsf = (float*)d_ws;
  float* stats = wsf;
  float* meanr = wsf + 1024;
  float* pmax  = wsf + 1152;
  unsigned short* tg = (unsigned short*)(wsf + 34016) + 9216;

  hipLaunchKernelGGL(k0_prep, dim3(4), dim3(256), 0, stream,
                     W_l, b_l, W_r, b_r, W_qk, W_v, b_v, W_t, wsf);
  hipLaunchKernelGGL(k1_attn, dim3(N_), dim3(256), 0, stream,
                     x, y, wsf, b_l, b_t, stats);
  hipLaunchKernelGGL(k2_stats, dim3(1), dim3(64), 0, stream, stats, meanr);
  hipLaunchKernelGGL(k3_max, dim3(512), dim3(256), 0, stream,
                     x, W_l, b_l, gamma, beta, tg, meanr, pmax);
  hipLaunchKernelGGL(k4_final, dim3(64), dim3(64), 0, stream, pmax, out);
}

// Round 5
// 208.559 us; speedup vs baseline: 3.1051x; 1.1933x over previous
//
#include <hip/hip_runtime.h>

#define B_ 64
#define N_ 8192

using short8 = __attribute__((ext_vector_type(8))) short;  // 8 bf16 (4 VGPRs)
using f32x4  = __attribute__((ext_vector_type(4))) float;

#define MFMA16(a, b, c) __builtin_amdgcn_mfma_f32_16x16x32_bf16((a), (b), (c), 0, 0, 0)

// round-half-up bf16: same 2^-9 max-rel-err bound as RNE, 2 VALU instrs
__device__ inline unsigned short f2bf(float f) {
  union { float f; unsigned int u; } v; v.f = f;
  return (unsigned short)((v.u + 0x8000u) >> 16);
}
__device__ inline float bf2f(unsigned int hi16_in_low) {
  union { unsigned int u; float f; } v; v.u = hi16_in_low << 16;
  return v.f;
}

// ws layout (f32 indices):
//   stats [0,1024) | meanr [1024,1152) | pmax [1152,66688)   (1024 blocks x 64)
//   ushort wb = (ushort*)(wsf+66688):
//     BM   [16 j][32]  @0     (M' = W_lq' W_rk'^T, kk 0..10 = M'[kk][j])
//     BL   [64 c][32]  @512   (kk 0..9 = W_l[kk][c], kk10 = b_l[c])
//     BRV2 [64 c][32]  @2560  (kk 0..12 = (W_r.W_v^T)[kk][c], kk13 = b_rv[c])
//     BT   [64 c][64]  @4608  (W_t)
//     tg   [B][N][64]  @8704  (t, bf16, b-major)
// A-tile k-slots: 0..9 = x, 10 = 1, 11..15 = 0, 16..28 = y, 29 = 1, 30,31 = 0.

// ---- k0: weight prep -----------------------------------------------------
__global__ void k0_prep(const float* __restrict__ W_l, const float* __restrict__ b_l,
                        const float* __restrict__ W_r, const float* __restrict__ b_r,
                        const float* __restrict__ W_qk, const float* __restrict__ W_v,
                        const float* __restrict__ b_v, const float* __restrict__ W_t,
                        float* __restrict__ wsf) {
  const int tid = threadIdx.x;
  unsigned short* wb   = (unsigned short*)(wsf + 66688);
  unsigned short* BM   = wb;
  unsigned short* BL   = wb + 512;
  unsigned short* BRV2 = wb + 2560;
  unsigned short* BT   = wb + 4608;
  if (blockIdx.x == 0) {
    __shared__ float Wlq[11 * 16], Wrk[14 * 16];
    for (int idx = tid; idx < 11 * 16; idx += 256) {
      int i = idx >> 4, d = idx & 15;
      const float* a = (i < 10) ? (W_l + i * 64) : b_l;
      float s = 0.f;
      for (int c = 0; c < 64; ++c) s = fmaf(a[c], W_qk[d * 64 + c], s);
      Wlq[idx] = s;
    }
    for (int idx = tid; idx < 14 * 16; idx += 256) {
      int j = idx >> 4, d = idx & 15;
      const float* a = (j < 13) ? (W_r + j * 64) : b_r;
      float s = 0.f;
      for (int c = 0; c < 64; ++c) s = fmaf(a[c], W_qk[d * 64 + c], s);
      Wrk[idx] = s;
    }
    __syncthreads();
    for (int idx = tid; idx < 512; idx += 256) {
      int j = idx >> 5, kk = idx & 31;
      unsigned short o = 0;
      if (j < 14 && kk < 11) {
        float s = 0.f;
        for (int d = 0; d < 16; ++d) s = fmaf(Wlq[kk * 16 + d], Wrk[j * 16 + d], s);
        o = f2bf(s);
      }
      BM[idx] = o;
    }
  } else if (blockIdx.x == 1) {
    for (int idx = tid; idx < 2048; idx += 256) {
      int c = idx >> 5, kk = idx & 31;
      unsigned short o = 0;
      if (kk < 13) {
        float s = 0.f;
        for (int j = 0; j < 64; ++j) s = fmaf(W_r[kk * 64 + j], W_v[c * 64 + j], s);
        o = f2bf(s);
      } else if (kk == 13) {
        float s = b_v[c];
        for (int j = 0; j < 64; ++j) s = fmaf(b_r[j], W_v[c * 64 + j], s);
        o = f2bf(s);
      }
      BRV2[idx] = o;
    }
  } else if (blockIdx.x == 2) {
    for (int idx = tid; idx < 2048; idx += 256) {
      int c = idx >> 5, kk = idx & 31;
      unsigned short o = 0;
      if (kk < 10) o = f2bf(W_l[kk * 64 + c]);
      else if (kk == 10) o = f2bf(b_l[c]);
      BL[idx] = o;
    }
    for (int i = tid; i < 1024; i += 256) wsf[i] = 0.f;
  } else {
    for (int i = tid; i < 4096; i += 256) BT[i] = f2bf(W_t[i]);
  }
}

// ---- k1: fused per-point chain, one block per n --------------------------
__global__ __launch_bounds__(256, 6)
void k1_attn(const float* __restrict__ x, const float* __restrict__ y,
             const float* __restrict__ wsf, const float* __restrict__ b_t,
             float* __restrict__ stats) {
  // LDS: 5120 + 2304 + 9216 + 2048 + 2048 = 20736 B -> 7 blocks/CU
  __shared__ __align__(16) short Axy[64 * 40];   // [b][k-slot]
  __shared__ __align__(16) short YT[16 * 72];    // yhat^T [j][e]
  __shared__ __align__(16) short awZ[4 * 1152];  // per-wave attn[16][72] -> Z overlay
  __shared__ __align__(16) short GU[4 * 256];    // per-wave G[16][16] -> U overlay
  __shared__ float scr[512];

  const unsigned short* wb   = (const unsigned short*)(wsf + 66688);
  const unsigned short* BM   = wb;
  const unsigned short* BL   = wb + 512;
  const unsigned short* BRV2 = wb + 2560;
  const unsigned short* BT   = wb + 4608;
  unsigned short* tg = (unsigned short*)(wsf + 66688) + 8704;

  const int n    = blockIdx.x;
  const int tid  = threadIdx.x;
  const int w    = tid >> 6;
  const int lane = tid & 63;
  const int l15  = lane & 15;
  const int q    = lane >> 4;
  const int r0   = w * 16;
  short* const aw = awZ + w * 1152;   // attn [16][72], later Z
  short* const gu = GU + w * 256;     // G [16][16], later U

  // ---- stage x,y into A-tile + yhat^T tile ----
  {
    const int b = tid >> 2, i = tid & 3;
    const float* xp = x + ((size_t)b * N_ + n) * 10;
    const float* yp = y + ((size_t)b * N_ + n) * 13;
    short* Ar = Axy + b * 40;
    Ar[i]     = (short)f2bf(xp[i]);
    Ar[i + 4] = (short)f2bf(xp[i + 4]);
    short v8 = 0;
    if (i < 2) v8 = (short)f2bf(xp[i + 8]);
    else if (i == 2) v8 = (short)0x3F80;            // xhat "1"
    Ar[i + 8]  = v8;
    Ar[i + 12] = 0;
    const short y0 = (short)f2bf(yp[i]);
    const short y1 = (short)f2bf(yp[i + 4]);
    const short y2 = (short)f2bf(yp[i + 8]);
    short y3 = 0;
    if (i == 0) y3 = (short)f2bf(yp[12]);
    else if (i == 1) y3 = (short)0x3F80;            // yhat "1"
    Ar[16 + i] = y0;  Ar[20 + i] = y1;  Ar[24 + i] = y2;  Ar[28 + i] = y3;
    YT[i * 72 + b] = y0;  YT[(i + 4) * 72 + b] = y1;
    YT[(i + 8) * 72 + b] = y2;  YT[(i + 12) * 72 + b] = y3;
  }
  __syncthreads();  // S1

  const short8 z8 = {0, 0, 0, 0, 0, 0, 0, 0};
  const f32x4 zero4 = {0.f, 0.f, 0.f, 0.f};
  const short8 aA = *(const short8*)&Axy[(r0 + l15) * 40 + q * 8];

  // ---- G = xhat M' (1 MFMA), X = xhat [W_l;b_l] (4 MFMAs) ----
  f32x4 G = MFMA16(aA, *(const short8*)&BM[l15 * 32 + q * 8], zero4);
  f32x4 X[4];
#pragma unroll
  for (int f = 0; f < 4; ++f)
    X[f] = MFMA16(aA, *(const short8*)&BL[(f * 16 + l15) * 32 + q * 8], zero4);
#pragma unroll
  for (int j = 0; j < 4; ++j) gu[(q * 4 + j) * 16 + l15] = (short)f2bf(G[j]);

  // ---- E = G yhat^T (B-frags straight from Axy y-slots) ----
  short8 aG = z8;
  if (q < 2) aG = *(const short8*)&gu[l15 * 16 + q * 8];
  f32x4 E[4];
#pragma unroll
  for (int f = 0; f < 4; ++f) {
    short8 bk = z8;
    if (q < 2) bk = *(const short8*)&Axy[(f * 16 + l15) * 40 + 16 + q * 8];
    E[f] = MFMA16(aG, bk, zero4);
  }

  // ---- softmax over e (|E|<<1: no max-subtract; validated R4) ----
  float inv_r[4];
#pragma unroll
  for (int j = 0; j < 4; ++j) {
    float s = 0.f;
#pragma unroll
    for (int f = 0; f < 4; ++f) { E[f][j] = __expf(E[f][j]); s += E[f][j]; }
    s += __shfl_xor(s, 1);
    s += __shfl_xor(s, 2);
    s += __shfl_xor(s, 4);
    s += __shfl_xor(s, 8);
    inv_r[j] = 1.0f / s;
  }
  // ---- column sums (L1 renorm) ----
#pragma unroll
  for (int f = 0; f < 4; ++f) {
    float cs = E[f][0] * inv_r[0] + E[f][1] * inv_r[1] + E[f][2] * inv_r[2] + E[f][3] * inv_r[3];
    cs += __shfl_xor(cs, 16);
    cs += __shfl_xor(cs, 32);
    if (lane < 16) scr[w * 64 + f * 16 + l15] = cs;
  }
  __syncthreads();  // S2
  float csvv[4];
#pragma unroll
  for (int f = 0; f < 4; ++f) {
    const int col = f * 16 + l15;
    csvv[f] = 1.0f / (1e-9f + scr[col] + scr[64 + col] + scr[128 + col] + scr[192 + col]);
  }
  // ---- attn -> per-wave LDS (A-layout source) ----
#pragma unroll
  for (int f = 0; f < 4; ++f)
#pragma unroll
    for (int j = 0; j < 4; ++j)
      aw[(q * 4 + j) * 72 + f * 16 + l15] = (short)f2bf(E[f][j] * inv_r[j] * csvv[f]);

  const short8 aA0 = *(const short8*)&aw[l15 * 72 + q * 8];
  const short8 aA1 = *(const short8*)&aw[l15 * 72 + 32 + q * 8];

  // ---- U = attn yhat (2 MFMAs); col 13 = rowsum carries b_rv ----
  f32x4 U = MFMA16(aA0, *(const short8*)&YT[l15 * 72 + q * 8], zero4);
  U = MFMA16(aA1, *(const short8*)&YT[l15 * 72 + 32 + q * 8], U);
#pragma unroll
  for (int j = 0; j < 4; ++j) gu[(q * 4 + j) * 16 + l15] = (short)f2bf(U[j]);  // overlay G
  short8 aU = z8;
  if (q < 2) aU = *(const short8*)&gu[l15 * 16 + q * 8];

  // ---- yr = U [W_rv;b_rv] ; Z = X - yr (overlay attn tile) ----
#pragma unroll
  for (int f = 0; f < 4; ++f) {
    f32x4 yr = MFMA16(aU, *(const short8*)&BRV2[(f * 16 + l15) * 32 + q * 8], zero4);
#pragma unroll
    for (int j = 0; j < 4; ++j)
      aw[(q * 4 + j) * 72 + f * 16 + l15] = (short)f2bf(X[f][j] - yr[j]);
  }

  // ---- t = Z W_t^T + b_t ; store [b][n][c] + stats ----
  const short8 aZ0 = *(const short8*)&aw[l15 * 72 + q * 8];
  const short8 aZ1 = *(const short8*)&aw[l15 * 72 + 32 + q * 8];
  f32x4 t[4];
#pragma unroll
  for (int f = 0; f < 4; ++f) {
    const int c = f * 16 + l15;
    const float bT = b_t[c];
    t[f] = MFMA16(aZ0, *(const short8*)&BT[c * 64 + q * 8], ((f32x4){bT, bT, bT, bT}));
    t[f] = MFMA16(aZ1, *(const short8*)&BT[c * 64 + 32 + q * 8], t[f]);
#pragma unroll
    for (int j = 0; j < 4; ++j)
      tg[(size_t)(r0 + q * 4 + j) * (N_ * 64) + (size_t)n * 64 + c] = f2bf(t[f][j]);
  }
  __syncthreads();  // S3: all csvv reads done before scr reuse
#pragma unroll
  for (int f = 0; f < 4; ++f) {
    float s = 0.f, ss = 0.f;
#pragma unroll
    for (int j = 0; j < 4; ++j) { s += t[f][j]; ss = fmaf(t[f][j], t[f][j], ss); }
    s  += __shfl_xor(s, 16);  s  += __shfl_xor(s, 32);
    ss += __shfl_xor(ss, 16); ss += __shfl_xor(ss, 32);
    if (lane < 16) {
      scr[w * 64 + f * 16 + l15]       = s;
      scr[256 + w * 64 + f * 16 + l15] = ss;
    }
  }
  __syncthreads();  // S4
  if (tid < 64) {
    const float s  = scr[tid] + scr[64 + tid] + scr[128 + tid] + scr[192 + tid];
    const float ss = scr[256 + tid] + scr[320 + tid] + scr[384 + tid] + scr[448 + tid];
    float* st = stats + (n & 7) * 128;
    atomicAdd(&st[tid], s);
    atomicAdd(&st[64 + tid], ss);
  }
}

// ---- k2: finalize BN stats ----------------------------------------------
__global__ void k2_stats(const float* __restrict__ stats, float* __restrict__ meanr) {
  const int c = threadIdx.x;
  if (c < 64) {
    float s = 0.f, ss = 0.f;
    for (int r = 0; r < 8; ++r) { s += stats[r * 128 + c]; ss += stats[r * 128 + 64 + c]; }
    const float inv = 1.0f / (float)(B_ * N_);
    const float mu = s * inv;
    const float var = fmaf(ss, inv, -mu * mu);
    meanr[c] = mu;
    meanr[64 + c] = rsqrtf(var + 1e-5f);
  }
}

// ---- k3: recompute X (f32), BN+ReLU+residual, partial max over n ---------
__global__ __launch_bounds__(256)
void k3_max(const float* __restrict__ x, const float* __restrict__ W_l,
            const float* __restrict__ b_l, const float* __restrict__ gamma,
            const float* __restrict__ beta, const unsigned short* __restrict__ tg,
            const float* __restrict__ meanr, float* __restrict__ pmax)
{
  const int b = blockIdx.x >> 4;      // 0..63
  const int chunk = blockIdx.x & 15;  // 512 n's each
  const int wv = threadIdx.x >> 6;
  const int lane = threadIdx.x & 63;
  const int c0 = (lane & 15) * 4;
  const int nsub = lane >> 4;
  float4 wl4[10];
#pragma unroll
  for (int k = 0; k < 10; ++k) wl4[k] = *(const float4*)&W_l[k * 64 + c0];
  const float4 bl  = *(const float4*)&b_l[c0];
  const float4 g   = *(const float4*)&gamma[c0];
  const float4 be  = *(const float4*)&beta[c0];
  const float4 mu  = *(const float4*)&meanr[c0];
  const float4 rs  = *(const float4*)&meanr[64 + c0];
  float4 grs, bmb;
  grs.x = g.x * rs.x; grs.y = g.y * rs.y; grs.z = g.z * rs.z; grs.w = g.w * rs.w;
  bmb.x = be.x - mu.x * grs.x; bmb.y = be.y - mu.y * grs.y;
  bmb.z = be.z - mu.z * grs.z; bmb.w = be.w - mu.w * grs.w;
  float4 m = {-1e30f, -1e30f, -1e30f, -1e30f};
  const size_t tgb = (size_t)b << 19;           // b * N * 64
  const int n0 = chunk * 512 + wv * 128 + nsub;
  for (int jj = 0; jj < 32; ++jj) {
    const int n = n0 + jj * 4;
    const uint2 tv = *(const uint2*)&tg[tgb + (size_t)n * 64 + c0];
    const float* xp = x + ((size_t)b * N_ + n) * 10;
    float4 X = bl;
#pragma unroll
    for (int k = 0; k < 10; ++k) {
      const float xk = xp[k];
      X.x = fmaf(xk, wl4[k].x, X.x); X.y = fmaf(xk, wl4[k].y, X.y);
      X.z = fmaf(xk, wl4[k].z, X.z); X.w = fmaf(xk, wl4[k].w, X.w);
    }
    const float t0 = bf2f(tv.x & 0xFFFFu), t1 = bf2f(tv.x >> 16);
    const float t2 = bf2f(tv.y & 0xFFFFu), t3 = bf2f(tv.y >> 16);
    m.x = fmaxf(m.x, X.x + fmaxf(fmaf(t0, grs.x, bmb.x), 0.f));
    m.y = fmaxf(m.y, X.y + fmaxf(fmaf(t1, grs.y, bmb.y), 0.f));
    m.z = fmaxf(m.z, X.z + fmaxf(fmaf(t2, grs.z, bmb.z), 0.f));
    m.w = fmaxf(m.w, X.w + fmaxf(fmaf(t3, grs.w, bmb.w), 0.f));
  }
  m.x = fmaxf(m.x, __shfl_xor(m.x, 16)); m.y = fmaxf(m.y, __shfl_xor(m.y, 16));
  m.z = fmaxf(m.z, __shfl_xor(m.z, 16)); m.w = fmaxf(m.w, __shfl_xor(m.w, 16));
  m.x = fmaxf(m.x, __shfl_xor(m.x, 32)); m.y = fmaxf(m.y, __shfl_xor(m.y, 32));
  m.z = fmaxf(m.z, __shfl_xor(m.z, 32)); m.w = fmaxf(m.w, __shfl_xor(m.w, 32));
  __shared__ float sm[4][64];
  if (lane < 16) *(float4*)&sm[wv][c0] = m;
  __syncthreads();
  if (threadIdx.x < 64) {
    const float r = fmaxf(fmaxf(sm[0][threadIdx.x], sm[1][threadIdx.x]),
                          fmaxf(sm[2][threadIdx.x], sm[3][threadIdx.x]));
    pmax[(size_t)blockIdx.x * 64 + threadIdx.x] = r;
  }
}

// ---- k4: final max over chunks -------------------------------------------
__global__ void k4_final(const float* __restrict__ pmax, float* __restrict__ out) {
  const int b = blockIdx.x, c = threadIdx.x;
  float m = -1e30f;
  for (int ch = 0; ch < 16; ++ch) m = fmaxf(m, pmax[((size_t)b * 16 + ch) * 64 + c]);
  out[b * 64 + c] = m;
}

// ---- launcher -------------------------------------------------------------
extern "C" void kernel_launch(void* const* d_in, const int* in_sizes, int n_in,
                              void* d_out, int out_size, void* d_ws, size_t ws_size,
                              hipStream_t stream) {
  const float* x     = (const float*)d_in[0];
  const float* y     = (const float*)d_in[1];
  const float* W_l   = (const float*)d_in[2];
  const float* b_l   = (const float*)d_in[3];
  const float* W_r   = (const float*)d_in[4];
  const float* b_r   = (const float*)d_in[5];
  const float* W_qk  = (const float*)d_in[6];
  const float* W_v   = (const float*)d_in[7];
  const float* b_v   = (const float*)d_in[8];
  const float* W_t   = (const float*)d_in[9];
  const float* b_t   = (const float*)d_in[10];
  const float* gamma = (const float*)d_in[11];
  const float* beta  = (const float*)d_in[12];
  float* out = (float*)d_out;

  float* wsf = (float*)d_ws;
  float* stats = wsf;
  float* meanr = wsf + 1024;
  float* pmax  = wsf + 1152;
  const unsigned short* tg = (const unsigned short*)(wsf + 66688) + 8704;

  hipLaunchKernelGGL(k0_prep, dim3(4), dim3(256), 0, stream,
                     W_l, b_l, W_r, b_r, W_qk, W_v, b_v, W_t, wsf);
  hipLaunchKernelGGL(k1_attn, dim3(N_), dim3(256), 0, stream,
                     x, y, wsf, b_t, stats);
  hipLaunchKernelGGL(k2_stats, dim3(1), dim3(64), 0, stream, stats, meanr);
  hipLaunchKernelGGL(k3_max, dim3(1024), dim3(256), 0, stream,
                     x, W_l, b_l, gamma, beta, tg, meanr, pmax);
  hipLaunchKernelGGL(k4_final, dim3(64), dim3(64), 0, stream, pmax, out);
}

// Round 6
// 207.229 us; speedup vs baseline: 3.1251x; 1.0064x over previous
//
#include <hip/hip_runtime.h>

#define B_ 64
#define N_ 8192

using short8 = __attribute__((ext_vector_type(8))) short;  // 8 bf16 (4 VGPRs)
using f32x4  = __attribute__((ext_vector_type(4))) float;

#define MFMA16(a, b, c) __builtin_amdgcn_mfma_f32_16x16x32_bf16((a), (b), (c), 0, 0, 0)

// round-half-up bf16: same 2^-9 max-rel-err bound as RNE, 2 VALU instrs
__device__ inline unsigned short f2bf(float f) {
  union { float f; unsigned int u; } v; v.f = f;
  return (unsigned short)((v.u + 0x8000u) >> 16);
}
__device__ inline float bf2f(unsigned int hi16_in_low) {
  union { unsigned int u; float f; } v; v.u = hi16_in_low << 16;
  return v.f;
}

// ws layout (f32 indices):
//   stats [0,1024) | meanr [1024,1152) | pmax [1152,66688)   (1024 blocks x 64)
//   ushort wb = (ushort*)(wsf+66688):
//     BM   [16 j][32]  @0     (M' = W_lq' W_rk'^T, kk 0..10 = M'[kk][j])
//     BL   [64 c][32]  @512   (kk 0..9 = W_l[kk][c], kk10 = b_l[c])
//     BRV2 [64 c][32]  @2560  (kk 0..12 = (W_r.W_v^T)[kk][c], kk13 = b_rv[c])
//     BT   [64 c][64]  @4608  (W_t)
//     tg   [B][N][64]  @8704  (t, bf16, b-major)
// A-tile k-slots: 0..9 = x, 10 = 1, 11..15 = 0, 16..28 = y, 29 = 1, 30,31 = 0.

// ---- k0: weight prep -----------------------------------------------------
__global__ void k0_prep(const float* __restrict__ W_l, const float* __restrict__ b_l,
                        const float* __restrict__ W_r, const float* __restrict__ b_r,
                        const float* __restrict__ W_qk, const float* __restrict__ W_v,
                        const float* __restrict__ b_v, const float* __restrict__ W_t,
                        float* __restrict__ wsf) {
  const int tid = threadIdx.x;
  unsigned short* wb   = (unsigned short*)(wsf + 66688);
  unsigned short* BM   = wb;
  unsigned short* BL   = wb + 512;
  unsigned short* BRV2 = wb + 2560;
  unsigned short* BT   = wb + 4608;
  if (blockIdx.x == 0) {
    __shared__ float Wlq[11 * 16], Wrk[14 * 16];
    for (int idx = tid; idx < 11 * 16; idx += 256) {
      int i = idx >> 4, d = idx & 15;
      const float* a = (i < 10) ? (W_l + i * 64) : b_l;
      float s = 0.f;
      for (int c = 0; c < 64; ++c) s = fmaf(a[c], W_qk[d * 64 + c], s);
      Wlq[idx] = s;
    }
    for (int idx = tid; idx < 14 * 16; idx += 256) {
      int j = idx >> 4, d = idx & 15;
      const float* a = (j < 13) ? (W_r + j * 64) : b_r;
      float s = 0.f;
      for (int c = 0; c < 64; ++c) s = fmaf(a[c], W_qk[d * 64 + c], s);
      Wrk[idx] = s;
    }
    __syncthreads();
    for (int idx = tid; idx < 512; idx += 256) {
      int j = idx >> 5, kk = idx & 31;
      unsigned short o = 0;
      if (j < 14 && kk < 11) {
        float s = 0.f;
        for (int d = 0; d < 16; ++d) s = fmaf(Wlq[kk * 16 + d], Wrk[j * 16 + d], s);
        o = f2bf(s);
      }
      BM[idx] = o;
    }
  } else if (blockIdx.x == 1) {
    for (int idx = tid; idx < 2048; idx += 256) {
      int c = idx >> 5, kk = idx & 31;
      unsigned short o = 0;
      if (kk < 13) {
        float s = 0.f;
        for (int j = 0; j < 64; ++j) s = fmaf(W_r[kk * 64 + j], W_v[c * 64 + j], s);
        o = f2bf(s);
      } else if (kk == 13) {
        float s = b_v[c];
        for (int j = 0; j < 64; ++j) s = fmaf(b_r[j], W_v[c * 64 + j], s);
        o = f2bf(s);
      }
      BRV2[idx] = o;
    }
  } else if (blockIdx.x == 2) {
    for (int idx = tid; idx < 2048; idx += 256) {
      int c = idx >> 5, kk = idx & 31;
      unsigned short o = 0;
      if (kk < 10) o = f2bf(W_l[kk * 64 + c]);
      else if (kk == 10) o = f2bf(b_l[c]);
      BL[idx] = o;
    }
    for (int i = tid; i < 1024; i += 256) wsf[i] = 0.f;
  } else {
    for (int i = tid; i < 4096; i += 256) BT[i] = f2bf(W_t[i]);
  }
}

// ---- k1: fused per-point chain, TWO points per block (lockstep) ----------
__global__ __launch_bounds__(256, 3)
void k1_attn(const float* __restrict__ x, const float* __restrict__ y,
             const float* __restrict__ wsf, const float* __restrict__ b_t,
             float* __restrict__ stats) {
  // LDS: 18688 shorts (37376 B) + 1024 f32 (4096 B) = 41472 B -> 3 blocks/CU
  __shared__ __align__(16) short lds[18688];
  __shared__ float scr[1024];
  // carve: Axy[2][64*40] | YT[2][16*72] | awZ[2][4][16*72] | GU[2][4][16*16]
  short* const Axy[2] = {lds, lds + 2560};
  short* const YTb[2] = {lds + 5120, lds + 6272};
  short* const awB    = lds + 7424;    // (p*4+w)*1152
  short* const guB    = lds + 16640;   // (p*4+w)*256

  const unsigned short* wb   = (const unsigned short*)(wsf + 66688);
  const unsigned short* BM   = wb;
  const unsigned short* BL   = wb + 512;
  const unsigned short* BRV2 = wb + 2560;
  const unsigned short* BT   = wb + 4608;
  unsigned short* tg = (unsigned short*)(wsf + 66688) + 8704;

  const int tid  = threadIdx.x;
  const int w    = tid >> 6;
  const int lane = tid & 63;
  const int l15  = lane & 15;
  const int q    = lane >> 4;
  const int r0   = w * 16;
  const int n0   = blockIdx.x * 2;
  short* const aw[2] = {awB + w * 1152, awB + (4 + w) * 1152};
  short* const gu[2] = {guB + w * 256,  guB + (4 + w) * 256};

  // ---- stage x,y for both points ----
  {
    const int b = tid >> 2, i = tid & 3;
#pragma unroll
    for (int p = 0; p < 2; ++p) {
      const float* xp = x + ((size_t)b * N_ + n0 + p) * 10;
      const float* yp = y + ((size_t)b * N_ + n0 + p) * 13;
      short* Ar = Axy[p] + b * 40;
      Ar[i]     = (short)f2bf(xp[i]);
      Ar[i + 4] = (short)f2bf(xp[i + 4]);
      short v8 = 0;
      if (i < 2) v8 = (short)f2bf(xp[i + 8]);
      else if (i == 2) v8 = (short)0x3F80;          // xhat "1"
      Ar[i + 8]  = v8;
      Ar[i + 12] = 0;
      const short y0 = (short)f2bf(yp[i]);
      const short y1 = (short)f2bf(yp[i + 4]);
      const short y2 = (short)f2bf(yp[i + 8]);
      short y3 = 0;
      if (i == 0) y3 = (short)f2bf(yp[12]);
      else if (i == 1) y3 = (short)0x3F80;          // yhat "1"
      Ar[16 + i] = y0;  Ar[20 + i] = y1;  Ar[24 + i] = y2;  Ar[28 + i] = y3;
      short* YT = YTb[p];
      YT[i * 72 + b] = y0;  YT[(i + 4) * 72 + b] = y1;
      YT[(i + 8) * 72 + b] = y2;  YT[(i + 12) * 72 + b] = y3;
    }
  }
  __syncthreads();  // S1

  const short8 z8 = {0, 0, 0, 0, 0, 0, 0, 0};
  const f32x4 zero4 = {0.f, 0.f, 0.f, 0.f};

  // hoisted weight B-frags (shared across both points)
  const short8 bmF = *(const short8*)&BM[l15 * 32 + q * 8];
  short8 blF[4];
#pragma unroll
  for (int f = 0; f < 4; ++f) blF[f] = *(const short8*)&BL[(f * 16 + l15) * 32 + q * 8];

  // ---- G = xhat M', X = xhat [W_l;b_l] ----
  f32x4 X[2][4];
#pragma unroll
  for (int p = 0; p < 2; ++p) {
    const short8 aA = *(const short8*)&Axy[p][(r0 + l15) * 40 + q * 8];
    f32x4 G = MFMA16(aA, bmF, zero4);
#pragma unroll
    for (int f = 0; f < 4; ++f) X[p][f] = MFMA16(aA, blF[f], zero4);
#pragma unroll
    for (int j = 0; j < 4; ++j) gu[p][(q * 4 + j) * 16 + l15] = (short)f2bf(G[j]);
  }

  // ---- E = G yhat^T ----
  f32x4 E[2][4];
#pragma unroll
  for (int p = 0; p < 2; ++p) {
    short8 aG = z8;
    if (q < 2) aG = *(const short8*)&gu[p][l15 * 16 + q * 8];
#pragma unroll
    for (int f = 0; f < 4; ++f) {
      short8 bk = z8;
      if (q < 2) bk = *(const short8*)&Axy[p][(f * 16 + l15) * 40 + 16 + q * 8];
      E[p][f] = MFMA16(aG, bk, zero4);
    }
  }

  // ---- softmax over e (no max-subtract; |E|<<1, validated R4/R5) ----
  float inv_r[2][4];
#pragma unroll
  for (int p = 0; p < 2; ++p)
#pragma unroll
    for (int j = 0; j < 4; ++j) {
      float s = 0.f;
#pragma unroll
      for (int f = 0; f < 4; ++f) { E[p][f][j] = __expf(E[p][f][j]); s += E[p][f][j]; }
      s += __shfl_xor(s, 1);
      s += __shfl_xor(s, 2);
      s += __shfl_xor(s, 4);
      s += __shfl_xor(s, 8);
      inv_r[p][j] = 1.0f / s;
    }
  // ---- column sums (L1 renorm) ----
#pragma unroll
  for (int p = 0; p < 2; ++p)
#pragma unroll
    for (int f = 0; f < 4; ++f) {
      float cs = E[p][f][0] * inv_r[p][0] + E[p][f][1] * inv_r[p][1] +
                 E[p][f][2] * inv_r[p][2] + E[p][f][3] * inv_r[p][3];
      cs += __shfl_xor(cs, 16);
      cs += __shfl_xor(cs, 32);
      if (lane < 16) scr[p * 256 + w * 64 + f * 16 + l15] = cs;
    }
  __syncthreads();  // S2

  // ---- attn tiles ----
#pragma unroll
  for (int p = 0; p < 2; ++p) {
#pragma unroll
    for (int f = 0; f < 4; ++f) {
      const int col = f * 16 + l15;
      const float* sp = scr + p * 256;
      const float csv = 1.0f / (1e-9f + sp[col] + sp[64 + col] + sp[128 + col] + sp[192 + col]);
#pragma unroll
      for (int j = 0; j < 4; ++j)
        aw[p][(q * 4 + j) * 72 + col] = (short)f2bf(E[p][f][j] * inv_r[p][j] * csv);
    }
  }

  // ---- U = attn yhat ; yr = U [W_rv;b_rv] ; Z = X - yr ----
  short8 brvF[4];
#pragma unroll
  for (int f = 0; f < 4; ++f) brvF[f] = *(const short8*)&BRV2[(f * 16 + l15) * 32 + q * 8];
#pragma unroll
  for (int p = 0; p < 2; ++p) {
    const short8 aA0 = *(const short8*)&aw[p][l15 * 72 + q * 8];
    const short8 aA1 = *(const short8*)&aw[p][l15 * 72 + 32 + q * 8];
    f32x4 U = MFMA16(aA0, *(const short8*)&YTb[p][l15 * 72 + q * 8], zero4);
    U = MFMA16(aA1, *(const short8*)&YTb[p][l15 * 72 + 32 + q * 8], U);
#pragma unroll
    for (int j = 0; j < 4; ++j) gu[p][(q * 4 + j) * 16 + l15] = (short)f2bf(U[j]);
    short8 aU = z8;
    if (q < 2) aU = *(const short8*)&gu[p][l15 * 16 + q * 8];
#pragma unroll
    for (int f = 0; f < 4; ++f) {
      f32x4 yr = MFMA16(aU, brvF[f], zero4);
#pragma unroll
      for (int j = 0; j < 4; ++j)
        aw[p][(q * 4 + j) * 72 + f * 16 + l15] = (short)f2bf(X[p][f][j] - yr[j]);
    }
  }

  // ---- t = Z W_t^T + b_t ; stats in registers ----
  f32x4 t[2][4];
  float sRed[2][4], ssRed[2][4];
#pragma unroll
  for (int p = 0; p < 2; ++p) {
    const short8 aZ0 = *(const short8*)&aw[p][l15 * 72 + q * 8];
    const short8 aZ1 = *(const short8*)&aw[p][l15 * 72 + 32 + q * 8];
#pragma unroll
    for (int f = 0; f < 4; ++f) {
      const int c = f * 16 + l15;
      const float bT = b_t[c];
      t[p][f] = MFMA16(aZ0, *(const short8*)&BT[c * 64 + q * 8], ((f32x4){bT, bT, bT, bT}));
      t[p][f] = MFMA16(aZ1, *(const short8*)&BT[c * 64 + 32 + q * 8], t[p][f]);
      float s = 0.f, ss = 0.f;
#pragma unroll
      for (int j = 0; j < 4; ++j) { s += t[p][f][j]; ss = fmaf(t[p][f][j], t[p][f][j], ss); }
      s  += __shfl_xor(s, 16);  s  += __shfl_xor(s, 32);
      ss += __shfl_xor(ss, 16); ss += __shfl_xor(ss, 32);
      sRed[p][f] = s; ssRed[p][f] = ss;
    }
  }
  __syncthreads();  // S3: colsum reads done; scr reusable
#pragma unroll
  for (int p = 0; p < 2; ++p)
#pragma unroll
    for (int f = 0; f < 4; ++f)
      if (lane < 16) {
        scr[p * 512 + w * 64 + f * 16 + l15]       = sRed[p][f];
        scr[p * 512 + 256 + w * 64 + f * 16 + l15] = ssRed[p][f];
      }
  __syncthreads();  // S4
  if (tid < 128) {
    const int p = tid >> 6, c = tid & 63;
    const float* sp = scr + p * 512;
    const float s  = sp[c] + sp[64 + c] + sp[128 + c] + sp[192 + c];
    const float ss = sp[256 + c] + sp[320 + c] + sp[384 + c] + sp[448 + c];
    float* st = stats + ((n0 + p) & 7) * 128;
    atomicAdd(&st[c], s);
    atomicAdd(&st[64 + c], ss);
  }
  // ---- tg stores LAST: no barrier waits on the scattered-store drain ----
#pragma unroll
  for (int p = 0; p < 2; ++p)
#pragma unroll
    for (int f = 0; f < 4; ++f)
#pragma unroll
      for (int j = 0; j < 4; ++j)
        tg[(size_t)(r0 + q * 4 + j) * (N_ * 64) + (size_t)(n0 + p) * 64 + f * 16 + l15] =
            f2bf(t[p][f][j]);
}

// ---- k2: finalize BN stats ----------------------------------------------
__global__ void k2_stats(const float* __restrict__ stats, float* __restrict__ meanr) {
  const int c = threadIdx.x;
  if (c < 64) {
    float s = 0.f, ss = 0.f;
    for (int r = 0; r < 8; ++r) { s += stats[r * 128 + c]; ss += stats[r * 128 + 64 + c]; }
    const float inv = 1.0f / (float)(B_ * N_);
    const float mu = s * inv;
    const float var = fmaf(ss, inv, -mu * mu);
    meanr[c] = mu;
    meanr[64 + c] = rsqrtf(var + 1e-5f);
  }
}

// ---- k3: recompute X (f32), BN+ReLU+residual, partial max over n ---------
__global__ __launch_bounds__(256)
void k3_max(const float* __restrict__ x, const float* __restrict__ W_l,
            const float* __restrict__ b_l, const float* __restrict__ gamma,
            const float* __restrict__ beta, const unsigned short* __restrict__ tg,
            const float* __restrict__ meanr, float* __restrict__ pmax)
{
  const int b = blockIdx.x >> 4;      // 0..63
  const int chunk = blockIdx.x & 15;  // 512 n's each
  const int wv = threadIdx.x >> 6;
  const int lane = threadIdx.x & 63;
  const int c0 = (lane & 15) * 4;
  const int nsub = lane >> 4;
  float4 wl4[10];
#pragma unroll
  for (int k = 0; k < 10; ++k) wl4[k] = *(const float4*)&W_l[k * 64 + c0];
  const float4 bl  = *(const float4*)&b_l[c0];
  const float4 g   = *(const float4*)&gamma[c0];
  const float4 be  = *(const float4*)&beta[c0];
  const float4 mu  = *(const float4*)&meanr[c0];
  const float4 rs  = *(const float4*)&meanr[64 + c0];
  float4 grs, bmb;
  grs.x = g.x * rs.x; grs.y = g.y * rs.y; grs.z = g.z * rs.z; grs.w = g.w * rs.w;
  bmb.x = be.x - mu.x * grs.x; bmb.y = be.y - mu.y * grs.y;
  bmb.z = be.z - mu.z * grs.z; bmb.w = be.w - mu.w * grs.w;
  float4 m = {-1e30f, -1e30f, -1e30f, -1e30f};
  const size_t tgb = (size_t)b << 19;           // b * N * 64
  const int n0 = chunk * 512 + wv * 128 + nsub;
  for (int jj = 0; jj < 32; ++jj) {
    const int n = n0 + jj * 4;
    const uint2 tv = *(const uint2*)&tg[tgb + (size_t)n * 64 + c0];
    const float* xp = x + ((size_t)b * N_ + n) * 10;
    float4 X = bl;
#pragma unroll
    for (int k = 0; k < 10; ++k) {
      const float xk = xp[k];
      X.x = fmaf(xk, wl4[k].x, X.x); X.y = fmaf(xk, wl4[k].y, X.y);
      X.z = fmaf(xk, wl4[k].z, X.z); X.w = fmaf(xk, wl4[k].w, X.w);
    }
    const float t0 = bf2f(tv.x & 0xFFFFu), t1 = bf2f(tv.x >> 16);
    const float t2 = bf2f(tv.y & 0xFFFFu), t3 = bf2f(tv.y >> 16);
    m.x = fmaxf(m.x, X.x + fmaxf(fmaf(t0, grs.x, bmb.x), 0.f));
    m.y = fmaxf(m.y, X.y + fmaxf(fmaf(t1, grs.y, bmb.y), 0.f));
    m.z = fmaxf(m.z, X.z + fmaxf(fmaf(t2, grs.z, bmb.z), 0.f));
    m.w = fmaxf(m.w, X.w + fmaxf(fmaf(t3, grs.w, bmb.w), 0.f));
  }
  m.x = fmaxf(m.x, __shfl_xor(m.x, 16)); m.y = fmaxf(m.y, __shfl_xor(m.y, 16));
  m.z = fmaxf(m.z, __shfl_xor(m.z, 16)); m.w = fmaxf(m.w, __shfl_xor(m.w, 16));
  m.x = fmaxf(m.x, __shfl_xor(m.x, 32)); m.y = fmaxf(m.y, __shfl_xor(m.y, 32));
  m.z = fmaxf(m.z, __shfl_xor(m.z, 32)); m.w = fmaxf(m.w, __shfl_xor(m.w, 32));
  __shared__ float sm[4][64];
  if (lane < 16) *(float4*)&sm[wv][c0] = m;
  __syncthreads();
  if (threadIdx.x < 64) {
    const float r = fmaxf(fmaxf(sm[0][threadIdx.x], sm[1][threadIdx.x]),
                          fmaxf(sm[2][threadIdx.x], sm[3][threadIdx.x]));
    pmax[(size_t)blockIdx.x * 64 + threadIdx.x] = r;
  }
}

// ---- k4: final max over chunks -------------------------------------------
__global__ void k4_final(const float* __restrict__ pmax, float* __restrict__ out) {
  const int b = blockIdx.x, c = threadIdx.x;
  float m = -1e30f;
  for (int ch = 0; ch < 16; ++ch) m = fmaxf(m, pmax[((size_t)b * 16 + ch) * 64 + c]);
  out[b * 64 + c] = m;
}

// ---- launcher -------------------------------------------------------------
extern "C" void kernel_launch(void* const* d_in, const int* in_sizes, int n_in,
                              void* d_out, int out_size, void* d_ws, size_t ws_size,
                              hipStream_t stream) {
  const float* x     = (const float*)d_in[0];
  const float* y     = (const float*)d_in[1];
  const float* W_l   = (const float*)d_in[2];
  const float* b_l   = (const float*)d_in[3];
  const float* W_r   = (const float*)d_in[4];
  const float* b_r   = (const float*)d_in[5];
  const float* W_qk  = (const float*)d_in[6];
  const float* W_v   = (const float*)d_in[7];
  const float* b_v   = (const float*)d_in[8];
  const float* W_t   = (const float*)d_in[9];
  const float* b_t   = (const float*)d_in[10];
  const float* gamma = (const float*)d_in[11];
  const float* beta  = (const float*)d_in[12];
  float* out = (float*)d_out;

  float* wsf = (float*)d_ws;
  float* stats = wsf;
  float* meanr = wsf + 1024;
  float* pmax  = wsf + 1152;
  const unsigned short* tg = (const unsigned short*)(wsf + 66688) + 8704;

  hipLaunchKernelGGL(k0_prep, dim3(4), dim3(256), 0, stream,
                     W_l, b_l, W_r, b_r, W_qk, W_v, b_v, W_t, wsf);
  hipLaunchKernelGGL(k1_attn, dim3(N_ / 2), dim3(256), 0, stream,
                     x, y, wsf, b_t, stats);
  hipLaunchKernelGGL(k2_stats, dim3(1), dim3(64), 0, stream, stats, meanr);
  hipLaunchKernelGGL(k3_max, dim3(1024), dim3(256), 0, stream,
                     x, W_l, b_l, gamma, beta, tg, meanr, pmax);
  hipLaunchKernelGGL(k4_final, dim3(64), dim3(64), 0, stream, pmax, out);
}